// Round 12
// baseline (126.507 us; speedup 1.0000x reference)
//
#include <hip/hip_runtime.h>
#include <hip/hip_bf16.h>
#include <stdint.h>

// SpatialMamba — round 12: LDS diet (alias xs-bf16 staging into Bp|Cp buffer)
// -> 4 blocks/CU, + u32 bf16-pair extraction in the scan loop.

constexpr int BN = 4, SL = 48;
constexpr int NPIX = BN * SL * SL;     // 9216
constexpr int L = SL;
constexpr int NSEQ = BN * SL;          // 192
constexpr int NBLK = 4 * NSEQ;         // 768
constexpr int PIXPB = 16;
constexpr int NPWB = NPIX / PIXPB;     // 576
constexpr int NPREP = 56;              // 14336 packed elements
constexpr int NPREB = NPWB + NPREP;    // 632

typedef __attribute__((ext_vector_type(8))) short short8;   // 8 bf16 frag
typedef __attribute__((ext_vector_type(4))) float f32x4;    // MFMA accum

#define DEVINL __device__ __forceinline__
DEVINL ushort f2b(float f) {           // f32 -> bf16 bits (RNE)
  uint u = __float_as_uint(f);
  return (ushort)((u + 0x7FFFu + ((u >> 16) & 1u)) >> 16);
}
DEVINL float b2f(ushort u) { return __uint_as_float(((uint)u) << 16); }

// ---------------- K_pre: zero d_out + in-proj + weight packing ----------------
__global__ __launch_bounds__(256) void k_pre(
    const float* __restrict__ x, const float* __restrict__ Win,
    const float* __restrict__ Wdt, const float* __restrict__ Wx,
    const float* __restrict__ Wout,
    float* __restrict__ xraw, float* __restrict__ slz,
    float* __restrict__ PMs, float* __restrict__ PO,
    ushort* __restrict__ PW2, float* __restrict__ out) {
  __shared__ float xf[PIXPB * 32];
  __shared__ float wt[32 * 129];
  int bid = blockIdx.x, tid = threadIdx.x;

  for (int e = bid * 256 + tid; e < NPIX * 32; e += NPREB * 256) out[e] = 0.f;

  if (bid < NPWB) {
    int pix0 = bid * PIXPB;
    for (int e = tid; e < PIXPB * 32; e += 256) xf[e] = x[pix0 * 32 + e];
    for (int e = tid; e < 4096; e += 256) {
      int j = e >> 5, k = e & 31;
      wt[k * 129 + j] = Win[e];
    }
    __syncthreads();
    int g = tid >> 6, lane = tid & 63;
    float s0[4] = {0.f, 0.f, 0.f, 0.f}, s1[4] = {0.f, 0.f, 0.f, 0.f};
    for (int k = 0; k < 32; ++k) {
      float w0 = wt[k * 129 + lane];
      float w1 = wt[k * 129 + 64 + lane];
      #pragma unroll
      for (int pp = 0; pp < 4; ++pp) {
        float xk = xf[(g * 4 + pp) * 32 + k];
        s0[pp] += w0 * xk;
        s1[pp] += w1 * xk;
      }
    }
    #pragma unroll
    for (int pp = 0; pp < 4; ++pp) {
      int pix = pix0 + g * 4 + pp;
      xraw[pix * 64 + lane] = s0[pp];
      float z = s1[pp];
      slz[pix * 64 + lane] = z / (1.f + __expf(-z));
    }
  } else {
    int e = (bid - NPWB) * 256 + tid;            // 0..14335
    if (e < 4096) {                              // PMs: delta-fold, f4-packed
      int i = e >> 6, d = e & 63;
      float s = 0.f;
      #pragma unroll 8
      for (int t = 0; t < 64; ++t) s += Wdt[i * 64 + t] * Wx[t * 64 + d];
      PMs[((d >> 2) * 64 + i) * 4 + (d & 3)] = s;
    } else if (e < 12288) {                      // PW2: bf16 B-frags for Bp/Cp
      int e2 = e - 4096;                         // [nt(8)][ks(2)][l(64)][j(8)]
      int j = e2 & 7, l = (e2 >> 3) & 63, ks = (e2 >> 9) & 1, nt = e2 >> 10;
      int k = ks * 32 + ((l >> 4) * 8) + j;      // contraction index
      int row = 64 + nt * 16 + (l & 15);         // Wx row (Bp/Cp block)
      PW2[e2] = f2b(Wx[row * 64 + k]);
    } else {                                     // PO: out-proj f4-packed
      int e2 = e - 12288; int c = e2 & 31, d = e2 >> 5;
      PO[((d >> 2) * 32 + c) * 4 + (d & 3)] = Wout[c * 64 + d];
    }
  }
}

// ---------------- K_scan ----------------
__global__ __launch_bounds__(256, 4) void k_scan(
    const float* __restrict__ xraw, const float* __restrict__ slz,
    const float* __restrict__ PMs, const ushort* __restrict__ PW2,
    const float* __restrict__ PO,
    const float* __restrict__ convw, const float* __restrict__ convb,
    const float* __restrict__ bdt, const float* __restrict__ Alog,
    const float* __restrict__ Dv, float* __restrict__ out) {
  __shared__ float R1[L * 64];                   // xr -> delta -> y   (12 KB)
  __shared__ float R3[L * 64];                   // xs f32            (12 KB)
  __shared__ __align__(16) ushort R2u[L * 136];  // xs-bf16 staging, then Bp|Cp (13 KB)
  ushort* R4u = R2u;   // alias: B writes swizzled xs-bf16 (first 48*64),
                       // C2a reads it, barrier, C2b overwrites region as Bp|Cp.

  int tid = threadIdx.x;
  int bid = blockIdx.x;
  int dir = bid / NSEQ;
  int seq = bid % NSEQ;
  int b = seq / SL, q = seq % SL;
  int pbase, pstride;
  if (dir == 0)      { pbase = (b * SL) * SL + q;           pstride = SL;  }
  else if (dir == 1) { pbase = (b * SL + SL - 1) * SL + q;  pstride = -SL; }
  else if (dir == 2) { pbase = (b * SL + q) * SL;           pstride = 1;   }
  else               { pbase = (b * SL + q) * SL + SL - 1;  pstride = -1;  }

  int wv = tid >> 6, lane = tid & 63;

  // Phase A: stage xraw rows into R1
  for (int t = wv; t < L; t += 4)
    R1[t * 64 + lane] = xraw[(pbase + t * pstride) * 64 + lane];
  __syncthreads();

  // Phase B: causal conv k=4 + silu -> R3 (f32) + R4u (bf16, swizzled)
  for (int e = tid; e < L * 64; e += 256) {
    int t = e >> 6, d = e & 63;
    float4 cw = reinterpret_cast<const float4*>(convw)[d];
    float s = convb[d] + R1[t * 64 + d] * cw.w;
    if (t >= 1) s += R1[(t - 1) * 64 + d] * cw.z;
    if (t >= 2) s += R1[(t - 2) * 64 + d] * cw.y;
    if (t >= 3) s += R1[(t - 3) * 64 + d] * cw.x;
    float xs = s / (1.f + __expf(-s));
    R3[t * 64 + d] = xs;
    R4u[t * 64 + (d ^ ((t & 7) << 3))] = f2b(xs);
  }
  __syncthreads();

  // Phase C2a: Bp|Cp MFMAs (reads R4u) -> acc regs (held across barrier)
  short8 bfrag[2][2];
  f32x4 acc[3][2];
  {
    const short8* pw8 = reinterpret_cast<const short8*>(PW2);
    #pragma unroll
    for (int ntl = 0; ntl < 2; ++ntl)
      #pragma unroll
      for (int ks = 0; ks < 2; ++ks)
        bfrag[ntl][ks] = pw8[((2 * wv + ntl) * 2 + ks) * 64 + lane];
    #pragma unroll
    for (int mt = 0; mt < 3; ++mt)
      #pragma unroll
      for (int ntl = 0; ntl < 2; ++ntl)
        acc[mt][ntl] = (f32x4){0.f, 0.f, 0.f, 0.f};
    #pragma unroll
    for (int mt = 0; mt < 3; ++mt) {
      int row = mt * 16 + (lane & 15);
      #pragma unroll
      for (int ks = 0; ks < 2; ++ks) {
        int within = (ks * 32 + ((lane >> 4) * 8)) ^ ((row & 7) << 3);
        short8 af = *reinterpret_cast<const short8*>(&R4u[row * 64 + within]);
        acc[mt][0] = __builtin_amdgcn_mfma_f32_16x16x32_bf16(af, bfrag[0][ks], acc[mt][0], 0, 0, 0);
        acc[mt][1] = __builtin_amdgcn_mfma_f32_16x16x32_bf16(af, bfrag[1][ks], acc[mt][1], 0, 0, 0);
      }
    }
  }
  __syncthreads();   // all R4u reads done; R2u region now reusable

  // Phase C1: delta = softplus(xs @ M^T + bdt) -> R1 (exact f32)
  {
    int tr = wv * 12;
    float aD[12];
    #pragma unroll
    for (int j = 0; j < 12; ++j) aD[j] = 0.f;
    const float4* pms = reinterpret_cast<const float4*>(PMs);
    for (int k4 = 0; k4 < 16; ++k4) {
      float4 wd = pms[k4 * 64 + lane];
      #pragma unroll
      for (int j = 0; j < 12; ++j) {
        float4 x4 = *reinterpret_cast<const float4*>(&R3[(tr + j) * 64 + k4 * 4]);
        aD[j] += wd.x * x4.x + wd.y * x4.y + wd.z * x4.z + wd.w * x4.w;
      }
    }
    float bdl = bdt[lane];
    #pragma unroll
    for (int j = 0; j < 12; ++j) {
      float s = aD[j] + bdl;
      s = (s > 15.f) ? s : __logf(1.f + __expf(s));
      R1[(tr + j) * 64 + lane] = s;
    }
  }

  // Phase C2b: write MFMA acc -> R2u as bf16 Bp|Cp
  #pragma unroll
  for (int mt = 0; mt < 3; ++mt)
    #pragma unroll
    for (int ntl = 0; ntl < 2; ++ntl)
      #pragma unroll
      for (int qq = 0; qq < 4; ++qq) {
        int t = mt * 16 + (lane >> 4) * 4 + qq;
        int rr = (2 * wv + ntl) * 16 + (lane & 15);
        R2u[t * 136 + rr] = f2b(acc[mt][ntl][qq]);
      }
  __syncthreads();

  // Phase D: 48-step scan. d = tid>>2, sg = tid&3 (16 states each).
  {
    int d = tid >> 2, sg = tid & 3;
    float A_[16];
    #pragma unroll
    for (int j = 0; j < 16; ++j) A_[j] = -__expf(Alog[d * 64 + sg * 16 + j]);
    float a0 = A_[0], dstep = A_[1] - A_[0];
    bool arith = true;
    #pragma unroll
    for (int j = 0; j < 16; ++j)
      arith = arith && (fabsf(A_[j] - (a0 + j * dstep)) <= 1e-3f * (1.f + fabsf(A_[j])));
    const float L2E = 1.44269504f;
    float a0L = a0 * L2E, ddL = dstep * L2E;
    float A2_[16];
    #pragma unroll
    for (int j = 0; j < 16; ++j) A2_[j] = A_[j] * L2E;
    float h[16];
    #pragma unroll
    for (int j = 0; j < 16; ++j) h[j] = 0.f;
    float Dd = Dv[d];

    for (int t = 0; t < L; ++t) {
      float dlt = R1[t * 64 + d];
      float bb = dlt * b2f(R2u[t * 136 + d]);
      const uint4* cp4 = reinterpret_cast<const uint4*>(&R2u[t * 136 + 64 + sg * 16]);
      uint4 ca = cp4[0], cb = cp4[1];
      float ab[16];
      if (arith) {
        float P = exp2f(dlt * a0L);
        float Rr = exp2f(dlt * ddL);
        float R2v = Rr * Rr, R4v = R2v * R2v, R8v = R4v * R4v;
        ab[0] = P;          ab[1] = P * Rr;
        ab[2] = P * R2v;    ab[3] = ab[1] * R2v;
        #pragma unroll
        for (int j = 0; j < 4; ++j) ab[4 + j] = ab[j] * R4v;
        #pragma unroll
        for (int j = 0; j < 8; ++j) ab[8 + j] = ab[j] * R8v;
      } else {
        #pragma unroll
        for (int j = 0; j < 16; ++j) ab[j] = exp2f(dlt * A2_[j]);
      }
      uint cw[8] = {ca.x, ca.y, ca.z, ca.w, cb.x, cb.y, cb.z, cb.w};
      float part = 0.f;
      #pragma unroll
      for (int p = 0; p < 8; ++p) {
        float clo = __uint_as_float(cw[p] << 16);           // state 2p
        float chi = __uint_as_float(cw[p] & 0xffff0000u);   // state 2p+1
        h[2 * p]     = ab[2 * p]     * h[2 * p]     + bb;
        h[2 * p + 1] = ab[2 * p + 1] * h[2 * p + 1] + bb;
        part += h[2 * p] * clo + h[2 * p + 1] * chi;
      }
      part += __shfl_xor(part, 1);
      part += __shfl_xor(part, 2);
      if (sg == 0) R1[t * 64 + d] = part + Dd * R3[t * 64 + d];   // y + D*xs
    }
  }
  __syncthreads();

  // P6a: gate with silu(z)
  for (int e = tid; e < L * 64; e += 256) {
    int t = e >> 6, d = e & 63;
    R1[t * 64 + d] *= slz[(pbase + t * pstride) * 64 + d];
  }
  __syncthreads();

  // P6b: out-projection + atomic accumulate
  for (int e = tid; e < L * 32; e += 256) {
    int t = e >> 5, c = e & 31;
    const float4* po = reinterpret_cast<const float4*>(PO);
    const float* yv = R1 + t * 64;
    float s = 0.f;
    #pragma unroll
    for (int d4 = 0; d4 < 16; ++d4) {
      float4 w = po[d4 * 32 + c];
      const float* yp = yv + d4 * 4;
      s += w.x * yp[0] + w.y * yp[1] + w.z * yp[2] + w.w * yp[3];
    }
    atomicAdd(&out[(pbase + t * pstride) * 32 + c], s);
  }
}

extern "C" void kernel_launch(void* const* d_in, const int* in_sizes, int n_in,
                              void* d_out, int out_size, void* d_ws, size_t ws_size,
                              hipStream_t stream) {
  const float* x     = (const float*)d_in[0];
  const float* Win   = (const float*)d_in[1];
  const float* convw = (const float*)d_in[2];
  const float* convb = (const float*)d_in[3];
  const float* Wx    = (const float*)d_in[4];
  const float* Wdt   = (const float*)d_in[5];
  const float* bdt   = (const float*)d_in[6];
  const float* Alog  = (const float*)d_in[7];
  const float* Dv    = (const float*)d_in[8];
  const float* Wout  = (const float*)d_in[9];

  float* xraw = (float*)d_ws;                 // [9216][64] f32
  float* slz  = xraw + NPIX * 64;             // [9216][64] f32
  float* PMs  = slz + NPIX * 64;              // 4096 f32
  float* PO   = PMs + 4096;                   // 2048 f32
  ushort* PW2 = (ushort*)(PO + 2048);         // 8192 bf16
  float* out  = (float*)d_out;

  k_pre<<<NPREB, 256, 0, stream>>>(x, Win, Wdt, Wx, Wout, xraw, slz,
                                   PMs, PO, PW2, out);
  k_scan<<<NBLK, 256, 0, stream>>>(xraw, slz, PMs, PW2, PO, convw, convb,
                                   bdt, Alog, Dv, out);
}

// Round 13
// 118.757 us; speedup vs baseline: 1.0653x; 1.0653x over previous
//
#include <hip/hip_runtime.h>
#include <hip/hip_bf16.h>
#include <stdint.h>

// SpatialMamba — round 13: delta GEMV onto MFMA (reuses Bp/Cp A-fragments).
// Phase C is now pure MFMA (18 MFMA/wave); C1's 192 ds_read_b128 + 768 FMA
// per thread are deleted. Delta lands in MFMA acc layout; softplus at write.

constexpr int BN = 4, SL = 48;
constexpr int NPIX = BN * SL * SL;     // 9216
constexpr int L = SL;
constexpr int NSEQ = BN * SL;          // 192
constexpr int NBLK = 4 * NSEQ;         // 768
constexpr int PIXPB = 16;
constexpr int NPWB = NPIX / PIXPB;     // 576
constexpr int NPREP = 56;              // 14336 packed elements
constexpr int NPREB = NPWB + NPREP;    // 632

typedef __attribute__((ext_vector_type(8))) short short8;   // 8 bf16 frag
typedef __attribute__((ext_vector_type(4))) float f32x4;    // MFMA accum

#define DEVINL __device__ __forceinline__
DEVINL ushort f2b(float f) {           // f32 -> bf16 bits (RNE)
  uint u = __float_as_uint(f);
  return (ushort)((u + 0x7FFFu + ((u >> 16) & 1u)) >> 16);
}
DEVINL float b2f(ushort u) { return __uint_as_float(((uint)u) << 16); }

// ---------------- K_pre: zero d_out + in-proj + weight packing ----------------
__global__ __launch_bounds__(256) void k_pre(
    const float* __restrict__ x, const float* __restrict__ Win,
    const float* __restrict__ Wdt, const float* __restrict__ Wx,
    const float* __restrict__ Wout,
    float* __restrict__ xraw, float* __restrict__ slz,
    ushort* __restrict__ PMd, float* __restrict__ PO,
    ushort* __restrict__ PW2, float* __restrict__ out) {
  __shared__ float xf[PIXPB * 32];
  __shared__ float wt[32 * 129];
  int bid = blockIdx.x, tid = threadIdx.x;

  for (int e = bid * 256 + tid; e < NPIX * 32; e += NPREB * 256) out[e] = 0.f;

  if (bid < NPWB) {
    int pix0 = bid * PIXPB;
    for (int e = tid; e < PIXPB * 32; e += 256) xf[e] = x[pix0 * 32 + e];
    for (int e = tid; e < 4096; e += 256) {
      int j = e >> 5, k = e & 31;
      wt[k * 129 + j] = Win[e];
    }
    __syncthreads();
    int g = tid >> 6, lane = tid & 63;
    float s0[4] = {0.f, 0.f, 0.f, 0.f}, s1[4] = {0.f, 0.f, 0.f, 0.f};
    for (int k = 0; k < 32; ++k) {
      float w0 = wt[k * 129 + lane];
      float w1 = wt[k * 129 + 64 + lane];
      #pragma unroll
      for (int pp = 0; pp < 4; ++pp) {
        float xk = xf[(g * 4 + pp) * 32 + k];
        s0[pp] += w0 * xk;
        s1[pp] += w1 * xk;
      }
    }
    #pragma unroll
    for (int pp = 0; pp < 4; ++pp) {
      int pix = pix0 + g * 4 + pp;
      xraw[pix * 64 + lane] = s0[pp];
      float z = s1[pp];
      slz[pix * 64 + lane] = z / (1.f + __expf(-z));
    }
  } else {
    int e = (bid - NPWB) * 256 + tid;            // 0..14335
    if (e < 4096) {                              // PMd: delta-fold, bf16 B-frags
      // [nt(4)][ks(2)][l(64)][j(8)]; i = nt*16+(l&15); k = ks*32+((l>>4)*8)+j
      int j = e & 7, l = (e >> 3) & 63, ks = (e >> 9) & 1, nt = e >> 10;
      int k = ks * 32 + ((l >> 4) * 8) + j;
      int i = nt * 16 + (l & 15);
      float s = 0.f;
      #pragma unroll 8
      for (int t = 0; t < 64; ++t) s += Wdt[i * 64 + t] * Wx[t * 64 + k];
      PMd[e] = f2b(s);
    } else if (e < 12288) {                      // PW2: bf16 B-frags for Bp/Cp
      int e2 = e - 4096;                         // [nt(8)][ks(2)][l(64)][j(8)]
      int j = e2 & 7, l = (e2 >> 3) & 63, ks = (e2 >> 9) & 1, nt = e2 >> 10;
      int k = ks * 32 + ((l >> 4) * 8) + j;
      int row = 64 + nt * 16 + (l & 15);
      PW2[e2] = f2b(Wx[row * 64 + k]);
    } else {                                     // PO: out-proj f4-packed
      int e2 = e - 12288; int c = e2 & 31, d = e2 >> 5;
      PO[((d >> 2) * 32 + c) * 4 + (d & 3)] = Wout[c * 64 + d];
    }
  }
}

// ---------------- K_scan ----------------
__global__ __launch_bounds__(256, 4) void k_scan(
    const float* __restrict__ xraw, const float* __restrict__ slz,
    const ushort* __restrict__ PMd, const ushort* __restrict__ PW2,
    const float* __restrict__ PO,
    const float* __restrict__ convw, const float* __restrict__ convb,
    const float* __restrict__ bdt, const float* __restrict__ Alog,
    const float* __restrict__ Dv, float* __restrict__ out) {
  __shared__ float R1[L * 64];                   // xr -> delta -> y   (12 KB)
  __shared__ float R3[L * 64];                   // xs f32            (12 KB)
  __shared__ __align__(16) ushort R2u[L * 136];  // xs-bf16 staging, then Bp|Cp (13 KB)
  ushort* R4u = R2u;   // alias: B writes swizzled xs-bf16; C-mfma reads it;
                       // barrier; region overwritten as Bp|Cp.

  int tid = threadIdx.x;
  int bid = blockIdx.x;
  int dir = bid / NSEQ;
  int seq = bid % NSEQ;
  int b = seq / SL, q = seq % SL;
  int pbase, pstride;
  if (dir == 0)      { pbase = (b * SL) * SL + q;           pstride = SL;  }
  else if (dir == 1) { pbase = (b * SL + SL - 1) * SL + q;  pstride = -SL; }
  else if (dir == 2) { pbase = (b * SL + q) * SL;           pstride = 1;   }
  else               { pbase = (b * SL + q) * SL + SL - 1;  pstride = -1;  }

  int wv = tid >> 6, lane = tid & 63;

  // Phase A: stage xraw rows into R1
  for (int t = wv; t < L; t += 4)
    R1[t * 64 + lane] = xraw[(pbase + t * pstride) * 64 + lane];
  __syncthreads();

  // Phase B: causal conv k=4 + silu -> R3 (f32) + R4u (bf16, swizzled)
  for (int e = tid; e < L * 64; e += 256) {
    int t = e >> 6, d = e & 63;
    float4 cw = reinterpret_cast<const float4*>(convw)[d];
    float s = convb[d] + R1[t * 64 + d] * cw.w;
    if (t >= 1) s += R1[(t - 1) * 64 + d] * cw.z;
    if (t >= 2) s += R1[(t - 2) * 64 + d] * cw.y;
    if (t >= 3) s += R1[(t - 3) * 64 + d] * cw.x;
    float xs = s / (1.f + __expf(-s));
    R3[t * 64 + d] = xs;
    R4u[t * 64 + (d ^ ((t & 7) << 3))] = f2b(xs);
  }
  __syncthreads();

  // Phase C-mfma: {Bp|Cp (2 ntl tiles) + delta (nt=wv tile)} per wave.
  // A-fragments (xs) shared by all three GEMMs.
  short8 bfrag[2][2], dfrag[2];
  f32x4 acc[3][2], accd[3];
  {
    const short8* pw8 = reinterpret_cast<const short8*>(PW2);
    const short8* pd8 = reinterpret_cast<const short8*>(PMd);
    #pragma unroll
    for (int ks = 0; ks < 2; ++ks) {
      bfrag[0][ks] = pw8[((2 * wv + 0) * 2 + ks) * 64 + lane];
      bfrag[1][ks] = pw8[((2 * wv + 1) * 2 + ks) * 64 + lane];
      dfrag[ks]    = pd8[(wv * 2 + ks) * 64 + lane];
    }
    #pragma unroll
    for (int mt = 0; mt < 3; ++mt) {
      acc[mt][0] = (f32x4){0.f, 0.f, 0.f, 0.f};
      acc[mt][1] = (f32x4){0.f, 0.f, 0.f, 0.f};
      accd[mt]   = (f32x4){0.f, 0.f, 0.f, 0.f};
    }
    #pragma unroll
    for (int mt = 0; mt < 3; ++mt) {
      int row = mt * 16 + (lane & 15);
      #pragma unroll
      for (int ks = 0; ks < 2; ++ks) {
        int within = (ks * 32 + ((lane >> 4) * 8)) ^ ((row & 7) << 3);
        short8 af = *reinterpret_cast<const short8*>(&R4u[row * 64 + within]);
        acc[mt][0] = __builtin_amdgcn_mfma_f32_16x16x32_bf16(af, bfrag[0][ks], acc[mt][0], 0, 0, 0);
        acc[mt][1] = __builtin_amdgcn_mfma_f32_16x16x32_bf16(af, bfrag[1][ks], acc[mt][1], 0, 0, 0);
        accd[mt]   = __builtin_amdgcn_mfma_f32_16x16x32_bf16(af, dfrag[ks],   accd[mt],   0, 0, 0);
      }
    }
  }
  __syncthreads();   // all R4u reads done; R2u region now reusable

  // Write-back: delta (softplus) -> R1; Bp|Cp (bf16) -> R2u
  {
    int ii = wv * 16 + (lane & 15);              // delta channel
    float bdl = bdt[ii];
    #pragma unroll
    for (int mt = 0; mt < 3; ++mt)
      #pragma unroll
      for (int qq = 0; qq < 4; ++qq) {
        int t = mt * 16 + (lane >> 4) * 4 + qq;
        float s = accd[mt][qq] + bdl;
        s = (s > 15.f) ? s : __logf(1.f + __expf(s));
        R1[t * 64 + ii] = s;
        int rr0 = (2 * wv) * 16 + (lane & 15);
        R2u[t * 136 + rr0]      = f2b(acc[mt][0][qq]);
        R2u[t * 136 + rr0 + 16] = f2b(acc[mt][1][qq]);
      }
  }
  __syncthreads();

  // Phase D: 48-step scan. d = tid>>2, sg = tid&3 (16 states each).
  {
    int d = tid >> 2, sg = tid & 3;
    float A_[16];
    #pragma unroll
    for (int j = 0; j < 16; ++j) A_[j] = -__expf(Alog[d * 64 + sg * 16 + j]);
    float a0 = A_[0], dstep = A_[1] - A_[0];
    bool arith = true;
    #pragma unroll
    for (int j = 0; j < 16; ++j)
      arith = arith && (fabsf(A_[j] - (a0 + j * dstep)) <= 1e-3f * (1.f + fabsf(A_[j])));
    const float L2E = 1.44269504f;
    float a0L = a0 * L2E, ddL = dstep * L2E;
    float A2_[16];
    #pragma unroll
    for (int j = 0; j < 16; ++j) A2_[j] = A_[j] * L2E;
    float h[16];
    #pragma unroll
    for (int j = 0; j < 16; ++j) h[j] = 0.f;
    float Dd = Dv[d];

    for (int t = 0; t < L; ++t) {
      float dlt = R1[t * 64 + d];
      float bb = dlt * b2f(R2u[t * 136 + d]);
      const uint4* cp4 = reinterpret_cast<const uint4*>(&R2u[t * 136 + 64 + sg * 16]);
      uint4 ca = cp4[0], cb = cp4[1];
      float ab[16];
      if (arith) {
        float P = exp2f(dlt * a0L);
        float Rr = exp2f(dlt * ddL);
        float R2v = Rr * Rr, R4v = R2v * R2v, R8v = R4v * R4v;
        ab[0] = P;          ab[1] = P * Rr;
        ab[2] = P * R2v;    ab[3] = ab[1] * R2v;
        #pragma unroll
        for (int j = 0; j < 4; ++j) ab[4 + j] = ab[j] * R4v;
        #pragma unroll
        for (int j = 0; j < 8; ++j) ab[8 + j] = ab[j] * R8v;
      } else {
        #pragma unroll
        for (int j = 0; j < 16; ++j) ab[j] = exp2f(dlt * A2_[j]);
      }
      uint cw[8] = {ca.x, ca.y, ca.z, ca.w, cb.x, cb.y, cb.z, cb.w};
      float part = 0.f;
      #pragma unroll
      for (int p = 0; p < 8; ++p) {
        float clo = __uint_as_float(cw[p] << 16);           // state 2p
        float chi = __uint_as_float(cw[p] & 0xffff0000u);   // state 2p+1
        h[2 * p]     = ab[2 * p]     * h[2 * p]     + bb;
        h[2 * p + 1] = ab[2 * p + 1] * h[2 * p + 1] + bb;
        part += h[2 * p] * clo + h[2 * p + 1] * chi;
      }
      part += __shfl_xor(part, 1);
      part += __shfl_xor(part, 2);
      if (sg == 0) R1[t * 64 + d] = part + Dd * R3[t * 64 + d];   // y + D*xs
    }
  }
  __syncthreads();

  // P6a: gate with silu(z)
  for (int e = tid; e < L * 64; e += 256) {
    int t = e >> 6, d = e & 63;
    R1[t * 64 + d] *= slz[(pbase + t * pstride) * 64 + d];
  }
  __syncthreads();

  // P6b: out-projection + atomic accumulate
  for (int e = tid; e < L * 32; e += 256) {
    int t = e >> 5, c = e & 31;
    const float4* po = reinterpret_cast<const float4*>(PO);
    const float* yv = R1 + t * 64;
    float s = 0.f;
    #pragma unroll
    for (int d4 = 0; d4 < 16; ++d4) {
      float4 w = po[d4 * 32 + c];
      const float* yp = yv + d4 * 4;
      s += w.x * yp[0] + w.y * yp[1] + w.z * yp[2] + w.w * yp[3];
    }
    atomicAdd(&out[(pbase + t * pstride) * 32 + c], s);
  }
}

extern "C" void kernel_launch(void* const* d_in, const int* in_sizes, int n_in,
                              void* d_out, int out_size, void* d_ws, size_t ws_size,
                              hipStream_t stream) {
  const float* x     = (const float*)d_in[0];
  const float* Win   = (const float*)d_in[1];
  const float* convw = (const float*)d_in[2];
  const float* convb = (const float*)d_in[3];
  const float* Wx    = (const float*)d_in[4];
  const float* Wdt   = (const float*)d_in[5];
  const float* bdt   = (const float*)d_in[6];
  const float* Alog  = (const float*)d_in[7];
  const float* Dv    = (const float*)d_in[8];
  const float* Wout  = (const float*)d_in[9];

  float* xraw = (float*)d_ws;                 // [9216][64] f32
  float* slz  = xraw + NPIX * 64;             // [9216][64] f32
  float* PO   = slz + NPIX * 64;              // 2048 f32
  ushort* PMd = (ushort*)(PO + 2048);         // 4096 bf16
  ushort* PW2 = PMd + 4096;                   // 8192 bf16
  float* out  = (float*)d_out;

  k_pre<<<NPREB, 256, 0, stream>>>(x, Win, Wdt, Wx, Wout, xraw, slz,
                                   PMd, PO, PW2, out);
  k_scan<<<NBLK, 256, 0, stream>>>(xraw, slz, PMd, PW2, PO, convw, convb,
                                   bdt, Alog, Dv, out);
}

// Round 15
// 112.748 us; speedup vs baseline: 1.1220x; 1.0533x over previous
//
#include <hip/hip_runtime.h>
#include <hip/hip_bf16.h>
#include <stdint.h>

// SpatialMamba — round 15: round-13 two-dispatch structure + f32 Bp/Cp LDS
// (extract-free phase D). Cooperative-launch experiment reverted (container
// killer suspect).

constexpr int BN = 4, SL = 48;
constexpr int NPIX = BN * SL * SL;     // 9216
constexpr int L = SL;
constexpr int NSEQ = BN * SL;          // 192
constexpr int NBLK = 4 * NSEQ;         // 768
constexpr int PIXPB = 16;
constexpr int NPWB = NPIX / PIXPB;     // 576
constexpr int NPREP = 56;              // 14336 packed elements
constexpr int NPREB = NPWB + NPREP;    // 632

typedef __attribute__((ext_vector_type(8))) short short8;   // 8 bf16 frag
typedef __attribute__((ext_vector_type(4))) float f32x4;    // MFMA accum

#define DEVINL __device__ __forceinline__
DEVINL ushort f2b(float f) {           // f32 -> bf16 bits (RNE)
  uint u = __float_as_uint(f);
  return (ushort)((u + 0x7FFFu + ((u >> 16) & 1u)) >> 16);
}

// ---------------- K_pre: zero d_out + in-proj + weight packing ----------------
__global__ __launch_bounds__(256) void k_pre(
    const float* __restrict__ x, const float* __restrict__ Win,
    const float* __restrict__ Wdt, const float* __restrict__ Wx,
    const float* __restrict__ Wout,
    float* __restrict__ xraw, float* __restrict__ slz,
    ushort* __restrict__ PMd, float* __restrict__ PO,
    ushort* __restrict__ PW2, float* __restrict__ out) {
  __shared__ float xf[PIXPB * 32];
  __shared__ float wt[32 * 129];
  int bid = blockIdx.x, tid = threadIdx.x;

  for (int e = bid * 256 + tid; e < NPIX * 32; e += NPREB * 256) out[e] = 0.f;

  if (bid < NPWB) {
    int pix0 = bid * PIXPB;
    for (int e = tid; e < PIXPB * 32; e += 256) xf[e] = x[pix0 * 32 + e];
    for (int e = tid; e < 4096; e += 256) {
      int j = e >> 5, k = e & 31;
      wt[k * 129 + j] = Win[e];
    }
    __syncthreads();
    int g = tid >> 6, lane = tid & 63;
    float s0[4] = {0.f, 0.f, 0.f, 0.f}, s1[4] = {0.f, 0.f, 0.f, 0.f};
    for (int k = 0; k < 32; ++k) {
      float w0 = wt[k * 129 + lane];
      float w1 = wt[k * 129 + 64 + lane];
      #pragma unroll
      for (int pp = 0; pp < 4; ++pp) {
        float xk = xf[(g * 4 + pp) * 32 + k];
        s0[pp] += w0 * xk;
        s1[pp] += w1 * xk;
      }
    }
    #pragma unroll
    for (int pp = 0; pp < 4; ++pp) {
      int pix = pix0 + g * 4 + pp;
      xraw[pix * 64 + lane] = s0[pp];
      float z = s1[pp];
      slz[pix * 64 + lane] = z / (1.f + __expf(-z));
    }
  } else {
    int e = (bid - NPWB) * 256 + tid;            // 0..14335
    if (e < 4096) {                              // PMd: delta-fold bf16 B-frags
      int j = e & 7, l = (e >> 3) & 63, ks = (e >> 9) & 1, nt = e >> 10;
      int k = ks * 32 + ((l >> 4) * 8) + j;
      int i = nt * 16 + (l & 15);
      float s = 0.f;
      #pragma unroll 8
      for (int t = 0; t < 64; ++t) s += Wdt[i * 64 + t] * Wx[t * 64 + k];
      PMd[e] = f2b(s);
    } else if (e < 12288) {                      // PW2: Bp/Cp bf16 B-frags
      int e2 = e - 4096;
      int j = e2 & 7, l = (e2 >> 3) & 63, ks = (e2 >> 9) & 1, nt = e2 >> 10;
      int k = ks * 32 + ((l >> 4) * 8) + j;
      int row = 64 + nt * 16 + (l & 15);
      PW2[e2] = f2b(Wx[row * 64 + k]);
    } else {                                     // PO: out-proj f4-packed
      int e2 = e - 12288; int c = e2 & 31, d = e2 >> 5;
      PO[((d >> 2) * 32 + c) * 4 + (d & 3)] = Wout[c * 64 + d];
    }
  }
}

// ---------------- K_scan ----------------
__global__ __launch_bounds__(256, 3) void k_scan(
    const float* __restrict__ xraw, const float* __restrict__ slz,
    const ushort* __restrict__ PMd, const ushort* __restrict__ PW2,
    const float* __restrict__ PO,
    const float* __restrict__ convw, const float* __restrict__ convb,
    const float* __restrict__ bdt, const float* __restrict__ Alog,
    const float* __restrict__ Dv, float* __restrict__ out) {
  __shared__ __align__(16) float SM[12672];      // 49.5 KB
  float* R1  = SM;            // xr -> delta -> y      [48*64]
  float* R3  = SM + 3072;     // xs f32                [48*64]
  float* BpF = SM + 6144;     // Bp f32 padded         [48*68]
  float* CpF = SM + 9408;     // Cp f32 padded         [48*68]
  ushort* stage = (ushort*)CpF;   // xs-bf16 swizzled  [48*64] (6 KB alias)

  int tid = threadIdx.x;
  int bid = blockIdx.x;
  int dir = bid / NSEQ;
  int seq = bid % NSEQ;
  int b = seq / SL, q = seq % SL;
  int pbase, pstride;
  if (dir == 0)      { pbase = (b * SL) * SL + q;           pstride = SL;  }
  else if (dir == 1) { pbase = (b * SL + SL - 1) * SL + q;  pstride = -SL; }
  else if (dir == 2) { pbase = (b * SL + q) * SL;           pstride = 1;   }
  else               { pbase = (b * SL + q) * SL + SL - 1;  pstride = -1;  }

  int wv = tid >> 6, lane = tid & 63;

  // A: stage xraw rows into R1
  for (int t = wv; t < L; t += 4)
    R1[t * 64 + lane] = xraw[(pbase + t * pstride) * 64 + lane];
  __syncthreads();

  // B: causal conv k=4 + silu -> R3 (f32) + stage (bf16, swizzled)
  for (int e = tid; e < L * 64; e += 256) {
    int t = e >> 6, d = e & 63;
    float4 cw = reinterpret_cast<const float4*>(convw)[d];
    float s = convb[d] + R1[t * 64 + d] * cw.w;
    if (t >= 1) s += R1[(t - 1) * 64 + d] * cw.z;
    if (t >= 2) s += R1[(t - 2) * 64 + d] * cw.y;
    if (t >= 3) s += R1[(t - 3) * 64 + d] * cw.x;
    float xs = s / (1.f + __expf(-s));
    R3[t * 64 + d] = xs;
    stage[t * 64 + (d ^ ((t & 7) << 3))] = f2b(xs);
  }
  __syncthreads();

  // C-mfma: {Bp|Cp (2 tiles) + delta (1 tile)} per wave; A-frags shared.
  short8 bfrag[2][2], dfrag[2];
  f32x4 acc[3][2], accd[3];
  {
    const short8* pw8 = reinterpret_cast<const short8*>(PW2);
    const short8* pd8 = reinterpret_cast<const short8*>(PMd);
    #pragma unroll
    for (int ks = 0; ks < 2; ++ks) {
      bfrag[0][ks] = pw8[((2 * wv + 0) * 2 + ks) * 64 + lane];
      bfrag[1][ks] = pw8[((2 * wv + 1) * 2 + ks) * 64 + lane];
      dfrag[ks]    = pd8[(wv * 2 + ks) * 64 + lane];
    }
    #pragma unroll
    for (int mt = 0; mt < 3; ++mt) {
      acc[mt][0] = (f32x4){0.f, 0.f, 0.f, 0.f};
      acc[mt][1] = (f32x4){0.f, 0.f, 0.f, 0.f};
      accd[mt]   = (f32x4){0.f, 0.f, 0.f, 0.f};
    }
    #pragma unroll
    for (int mt = 0; mt < 3; ++mt) {
      int row = mt * 16 + (lane & 15);
      #pragma unroll
      for (int ks = 0; ks < 2; ++ks) {
        int within = (ks * 32 + ((lane >> 4) * 8)) ^ ((row & 7) << 3);
        short8 af = *reinterpret_cast<const short8*>(&stage[row * 64 + within]);
        acc[mt][0] = __builtin_amdgcn_mfma_f32_16x16x32_bf16(af, bfrag[0][ks], acc[mt][0], 0, 0, 0);
        acc[mt][1] = __builtin_amdgcn_mfma_f32_16x16x32_bf16(af, bfrag[1][ks], acc[mt][1], 0, 0, 0);
        accd[mt]   = __builtin_amdgcn_mfma_f32_16x16x32_bf16(af, dfrag[ks],   accd[mt],   0, 0, 0);
      }
    }
  }
  __syncthreads();   // stage reads done; CpF region reusable

  // Write-back: delta (softplus) -> R1; Bp, Cp (f32) -> BpF/CpF
  {
    int ii = wv * 16 + (lane & 15);
    float bdl = bdt[ii];
    float* dst = (wv < 2) ? BpF : CpF;
    int cb = ((2 * wv) & 3) * 16 + (lane & 15);
    #pragma unroll
    for (int mt = 0; mt < 3; ++mt)
      #pragma unroll
      for (int qq = 0; qq < 4; ++qq) {
        int t = mt * 16 + (lane >> 4) * 4 + qq;
        float s = accd[mt][qq] + bdl;
        s = (s > 15.f) ? s : __logf(1.f + __expf(s));
        R1[t * 64 + ii] = s;
        dst[t * 68 + cb]      = acc[mt][0][qq];
        dst[t * 68 + cb + 16] = acc[mt][1][qq];
      }
  }
  __syncthreads();

  // D: 48-step scan. d = tid>>2, sg = tid&3 (16 states each). All f32 LDS.
  {
    int d = tid >> 2, sg = tid & 3;
    float A_[16];
    #pragma unroll
    for (int j = 0; j < 16; ++j) A_[j] = -__expf(Alog[d * 64 + sg * 16 + j]);
    float a0 = A_[0], dstep = A_[1] - A_[0];
    bool arith = true;
    #pragma unroll
    for (int j = 0; j < 16; ++j)
      arith = arith && (fabsf(A_[j] - (a0 + j * dstep)) <= 1e-3f * (1.f + fabsf(A_[j])));
    const float L2E = 1.44269504f;
    float a0L = a0 * L2E, ddL = dstep * L2E;
    float A2_[16];
    #pragma unroll
    for (int j = 0; j < 16; ++j) A2_[j] = A_[j] * L2E;
    float h[16];
    #pragma unroll
    for (int j = 0; j < 16; ++j) h[j] = 0.f;
    float Dd = Dv[d];

    for (int t = 0; t < L; ++t) {
      float dlt = R1[t * 64 + d];
      float bb  = dlt * BpF[t * 68 + d];
      const float4* cp4 = reinterpret_cast<const float4*>(&CpF[t * 68 + sg * 16]);
      float4 c0 = cp4[0], c1 = cp4[1], c2 = cp4[2], c3 = cp4[3];
      float ca[16] = {c0.x, c0.y, c0.z, c0.w, c1.x, c1.y, c1.z, c1.w,
                      c2.x, c2.y, c2.z, c2.w, c3.x, c3.y, c3.z, c3.w};
      float ab[16];
      if (arith) {
        float P  = exp2f(dlt * a0L);
        float Rr = exp2f(dlt * ddL);
        float R2v = Rr * Rr, R4v = R2v * R2v, R8v = R4v * R4v;
        ab[0] = P;          ab[1] = P * Rr;
        ab[2] = P * R2v;    ab[3] = ab[1] * R2v;
        #pragma unroll
        for (int j = 0; j < 4; ++j) ab[4 + j] = ab[j] * R4v;
        #pragma unroll
        for (int j = 0; j < 8; ++j) ab[8 + j] = ab[j] * R8v;
      } else {
        #pragma unroll
        for (int j = 0; j < 16; ++j) ab[j] = exp2f(dlt * A2_[j]);
      }
      float part = 0.f;
      #pragma unroll
      for (int j = 0; j < 16; ++j) {
        h[j] = ab[j] * h[j] + bb;
        part += h[j] * ca[j];
      }
      part += __shfl_xor(part, 1);
      part += __shfl_xor(part, 2);
      if (sg == 0) R1[t * 64 + d] = part + Dd * R3[t * 64 + d];   // y + D*xs
    }
  }
  __syncthreads();

  // P6a: gate with silu(z)
  for (int e = tid; e < L * 64; e += 256) {
    int t = e >> 6, d = e & 63;
    R1[t * 64 + d] *= slz[(pbase + t * pstride) * 64 + d];
  }
  __syncthreads();

  // P6b: out-projection + atomic accumulate
  for (int e = tid; e < L * 32; e += 256) {
    int t = e >> 5, c = e & 31;
    const float4* po = reinterpret_cast<const float4*>(PO);
    const float* yv = R1 + t * 64;
    float s = 0.f;
    #pragma unroll
    for (int d4 = 0; d4 < 16; ++d4) {
      float4 w = po[d4 * 32 + c];
      const float* yp = yv + d4 * 4;
      s += w.x * yp[0] + w.y * yp[1] + w.z * yp[2] + w.w * yp[3];
    }
    atomicAdd(&out[(pbase + t * pstride) * 32 + c], s);
  }
}

extern "C" void kernel_launch(void* const* d_in, const int* in_sizes, int n_in,
                              void* d_out, int out_size, void* d_ws, size_t ws_size,
                              hipStream_t stream) {
  const float* x     = (const float*)d_in[0];
  const float* Win   = (const float*)d_in[1];
  const float* convw = (const float*)d_in[2];
  const float* convb = (const float*)d_in[3];
  const float* Wx    = (const float*)d_in[4];
  const float* Wdt   = (const float*)d_in[5];
  const float* bdt   = (const float*)d_in[6];
  const float* Alog  = (const float*)d_in[7];
  const float* Dv    = (const float*)d_in[8];
  const float* Wout  = (const float*)d_in[9];

  float* xraw = (float*)d_ws;                 // [9216][64] f32
  float* slz  = xraw + NPIX * 64;             // [9216][64] f32
  float* PO   = slz + NPIX * 64;              // 2048 f32
  ushort* PMd = (ushort*)(PO + 2048);         // 4096 bf16
  ushort* PW2 = PMd + 4096;                   // 8192 bf16
  float* out  = (float*)d_out;

  k_pre<<<NPREB, 256, 0, stream>>>(x, Win, Wdt, Wx, Wout, xraw, slz,
                                   PMd, PO, PW2, out);
  k_scan<<<NBLK, 256, 0, stream>>>(xraw, slz, PMd, PW2, PO, convw, convb,
                                   bdt, Alog, Dv, out);
}